// Round 3
// baseline (258.545 us; speedup 1.0000x reference)
//
#include <hip/hip_runtime.h>
#include <math.h>

// FastFood upsample.
// y[b] = fwht_1024(z[b] * BB[:1024]);  m1[j] = y[j & 1023]  (input sparse).
// H_{2^20} = H_{2^10} (x) H_{2^10}:
//   pass1: U[b][kh][jl] = FWHT_1024 over kl of t[b][kh][kl], t = y[Pi&1023]*GG
//   pass2: out[b][jh][jl] = FWHT_1024 over kh of U[b][kh][jl], scaled+remapped
// FWHT-1024 per wave, v[16] regs, i = r*64+lane (mapping M0):
//   bits 6-9: in-register H16 | bits 0,1: DPP quad_perm | bits 2-5: one batched
//   per-wave LDS transpose (XOR-swizzled, conflict-free) + in-register H16.
// Ends in mapping M1: v[rp] = F[(lane&3) | (rp<<2) | ((lane>>2)<<6)].

#define TS 17            // staging tile word-stride (16 cols + 1 pad)
#define TOTAL_DIM 984064
#define OUT_B0 786432    // 768*1024
#define OUT_B1 787200    // + 768
#define OUT_B2 983808    // + 192*1024
#define OFF1 25165824L   // 32*786432
#define OFF2 25190400L   // + 32*768
#define OFF3 31481856L   // + 32*196608

template<int CTRL>
__device__ __forceinline__ float pdpp(float x) {
    return __int_as_float(__builtin_amdgcn_update_dpp(
        0, __float_as_int(x), CTRL, 0xF, 0xF, true));
}

// H16 over the 16-register index (4 butterfly stages, pure VALU).
__device__ __forceinline__ void h16(float v[16]) {
    #pragma unroll
    for (int m = 1; m <= 8; m <<= 1) {
        #pragma unroll
        for (int r = 0; r < 16; ++r) {
            if (!(r & m)) {
                float a = v[r], b = v[r | m];
                v[r] = a + b;
                v[r | m] = a - b;
            }
        }
    }
}

// Butterflies on lane bits 0,1 via DPP quad_perm.
__device__ __forceinline__ void dpp2(float v[16], int lane) {
    const float s1 = (lane & 1) ? -1.f : 1.f;
    const float s2 = (lane & 2) ? -1.f : 1.f;
    #pragma unroll
    for (int r = 0; r < 16; ++r) { float p = pdpp<0xB1>(v[r]); v[r] = fmaf(s1, v[r], p); }
    #pragma unroll
    for (int r = 0; r < 16; ++r) { float p = pdpp<0x4E>(v[r]); v[r] = fmaf(s2, v[r], p); }
}

// Batched per-wave transpose through a private 1024-word LDS slice.
// In:  v[r]  = E[r*64 + lane]                    (M0)
// Out: v[rp] = E[(lane&3) | (rp<<2) | ((lane>>2)<<6)]   (M1)
// phys(i) = i ^ (((i>>6)&7)<<2): conflict-free on both sides.
__device__ __forceinline__ void wave_transpose(float v[16], float* ws, int lane) {
    #pragma unroll
    for (int r = 0; r < 16; ++r) {
        const int i = r * 64 + lane;
        ws[i ^ ((r & 7) << 2)] = v[r];
    }
    #pragma unroll
    for (int rp = 0; rp < 16; ++rp) {
        const int i = (lane & 3) | (rp << 2) | ((lane >> 2) << 6);
        v[rp] = ws[i ^ (((lane >> 2) & 7) << 2)];
    }
}

// Full FWHT-1024: M0 in, M1 out.
__device__ __forceinline__ void fwht1024(float v[16], float* ws, int lane) {
    h16(v);            // bits 6-9
    dpp2(v, lane);     // bits 0,1
    wave_transpose(v, ws, lane);
    h16(v);            // bits 2-5
}

// Shared out-tile swizzle: A = i*TS + col, phys2 = A ^ (((i>>6)&7)<<2).
__device__ __forceinline__ int phys2(int i, int col) {
    return (i * TS + col) ^ (((i >> 6) & 7) << 2);
}

// Pass 0: y_t[i*32+b] = fwht_1024(z[b]*BB[:1024])[i].  2 blocks x 16 waves.
__global__ __launch_bounds__(1024) void k_y(const float* __restrict__ z,
                                            const float* __restrict__ BBv,
                                            float* __restrict__ y_t) {
    __shared__ float tile[1024 * TS];
    const int tid = threadIdx.x;
    const int lane = tid & 63, w = tid >> 6;
    const int b = (blockIdx.x << 4) + w;
    float v[16];
    #pragma unroll
    for (int r = 0; r < 16; ++r) {
        const int i = r * 64 + lane;
        v[r] = z[(b << 10) + i] * BBv[i];
    }
    fwht1024(v, &tile[w << 10], lane);
    __syncthreads();                      // all private-slice reads done
    #pragma unroll
    for (int rp = 0; rp < 16; ++rp) {
        const int i = (lane & 3) | (rp << 2) | ((lane >> 2) << 6);
        tile[phys2(i, w)] = v[rp];
    }
    __syncthreads();
    const int bcol = tid & 15, i0 = tid >> 4;
    #pragma unroll 4
    for (int s = 0; s < 16; ++s) {
        const int i = i0 + (s << 6);
        y_t[(i << 5) + (blockIdx.x << 4) + bcol] = tile[phys2(i, bcol)];
    }
}

// Pass 1: block = (kh, bgroup of 16 b). Coalesced gather stage -> wave FWHT
// (M1 end) -> direct quad-segment U write.
__global__ __launch_bounds__(1024, 8) void k_pass1(const float* __restrict__ y_t,
                                                   const float* __restrict__ GG,
                                                   const int* __restrict__ Pi,
                                                   float* __restrict__ U) {
    __shared__ float tile[1024 * TS];
    __shared__ float g_s[1024];
    __shared__ int   p_s[1024];
    const int tid = threadIdx.x;
    const int kh = blockIdx.x, bg = blockIdx.y;
    p_s[tid] = Pi[(kh << 10) + tid] & 1023;
    g_s[tid] = GG[(kh << 10) + tid];
    __syncthreads();
    const int b = tid & 15, kl0 = tid >> 4;
    #pragma unroll 4
    for (int s = 0; s < 16; ++s) {
        const int kl = kl0 + (s << 6);
        tile[kl * TS + b] = y_t[(p_s[kl] << 5) + (bg << 4) + b] * g_s[kl];
    }
    __syncthreads();
    const int lane = tid & 63, w = tid >> 6;
    float v[16];
    #pragma unroll
    for (int r = 0; r < 16; ++r) v[r] = tile[(r * 64 + lane) * TS + w];
    h16(v);
    dpp2(v, lane);
    __syncthreads();                      // all staging reads done before reuse
    wave_transpose(v, &tile[w << 10], lane);
    h16(v);
    const long ub = ((long)((bg << 4) + w) << 20) + ((long)kh << 10);
    float* Up = U + ub + (lane & 3) + ((lane >> 2) << 6);
    #pragma unroll
    for (int rp = 0; rp < 16; ++rp) Up[rp << 2] = v[rp];
}

// Pass 2: block = (jl-tile of 16, b). Stage U -> wave FWHT over kh (M1 end)
// -> swizzled shared out-transpose -> coalesced remapped store.
__global__ __launch_bounds__(1024, 8) void k_pass2(const float* __restrict__ U,
                                                   const float* __restrict__ divisor,
                                                   float* __restrict__ out) {
    __shared__ float tile[1024 * TS];
    const int tid = threadIdx.x;
    const int jl0 = blockIdx.x << 4;   // 0..1008 step 16
    const int bb  = blockIdx.y;        // 0..31
    const float* Ubp = U + ((long)bb << 20);
    const int jl = tid & 15, k0 = tid >> 4;
    #pragma unroll 4
    for (int s = 0; s < 16; ++s) {
        const int kh = k0 + (s << 6);
        tile[kh * TS + jl] = Ubp[((long)kh << 10) + jl0 + jl];
    }
    __syncthreads();
    const int lane = tid & 63, w = tid >> 6;
    float v[16];
    #pragma unroll
    for (int r = 0; r < 16; ++r) v[r] = tile[(r * 64 + lane) * TS + w];
    h16(v);
    dpp2(v, lane);
    __syncthreads();                      // staging reads done before reuse
    wave_transpose(v, &tile[w << 10], lane);
    h16(v);
    const float inv = 1.0f / (divisor[0] * sqrtf((float)TOTAL_DIM / 1048576.0f));
    __syncthreads();                      // private-slice reads done before out-tile
    #pragma unroll
    for (int rp = 0; rp < 16; ++rp) {
        const int jh = (lane & 3) | (rp << 2) | ((lane >> 2) << 6);
        tile[phys2(jh, w)] = v[rp] * inv;
    }
    __syncthreads();
    #pragma unroll 2
    for (int s = 0; s < 16; ++s) {
        const int jh = k0 + (s << 6);
        if (jh <= 960) {                                  // TOTAL = 961*1024
            const int j = (jh << 10) + jl0 + jl;
            long oidx;
            if (j < OUT_B0)      oidx = (long)bb * 786432 + j;
            else if (j < OUT_B1) oidx = OFF1 + (long)bb * 768 + (j - OUT_B0);
            else if (j < OUT_B2) oidx = OFF2 + (long)bb * 196608 + (j - OUT_B1);
            else                 oidx = OFF3 + (long)bb * 256 + (j - OUT_B2);
            out[oidx] = tile[phys2(jh, jl)];
        }
    }
}

extern "C" void kernel_launch(void* const* d_in, const int* in_sizes, int n_in,
                              void* d_out, int out_size, void* d_ws, size_t ws_size,
                              hipStream_t stream) {
    const float* z   = (const float*)d_in[0];   // [32,1024]
    const float* BBv = (const float*)d_in[1];   // [2^20]
    const float* GG  = (const float*)d_in[2];   // [2^20]
    const float* dv  = (const float*)d_in[3];   // [1]
    const int*   Pi  = (const int*)d_in[4];     // [2^20]
    float* out = (float*)d_out;

    float* y_t = (float*)d_ws;                              // 32*1024 f32 = 128 KB
    float* U   = (float*)((char*)d_ws + (size_t)131072);    // 32*2^20 f32 = 128 MB

    k_y<<<2, 1024, 0, stream>>>(z, BBv, y_t);
    k_pass1<<<dim3(1024, 2), 1024, 0, stream>>>(y_t, GG, Pi, U);
    k_pass2<<<dim3(64, 32), 1024, 0, stream>>>(U, dv, out);
}

// Round 4
// 238.686 us; speedup vs baseline: 1.0832x; 1.0832x over previous
//
#include <hip/hip_runtime.h>
#include <hip/hip_fp16.h>
#include <math.h>

// FastFood upsample.
// y[b] = fwht_1024(z[b] * BB[:1024]);  m1[j] = y[j & 1023]  (input sparse).
// H_{2^20} = H_{2^10} (x) H_{2^10}:
//   pass1: U[b][kh][jl] = FWHT_1024 over kl of t[b][kh][kl], t = y[Pi&1023]*GG
//   pass2: out[b][jh][jl] = FWHT_1024 over kh of U[b][kh][jl], scaled+remapped
// U is stored fp16 (sigma(U)~1024, fp16 range 64 sigma; quant error ~1e-5 at
// the output vs 3.6e-3 threshold) -> halves the U HBM round trip.
// FWHT-1024 per wave, v[16] regs, i = r*64+lane (mapping M0):
//   bits 6-9: in-register H16 | bits 0,1: DPP quad_perm | bits 2-5: one batched
//   per-wave LDS transpose (XOR-swizzled, conflict-free) + in-register H16.
// Ends in mapping M1: v[rp] = F[(lane&3) | (rp<<2) | ((lane>>2)<<6)].

#define TS 17            // staging tile word-stride (16 cols + 1 pad)
#define TOTAL_DIM 984064
#define OUT_B0 786432    // 768*1024
#define OUT_B1 787200    // + 768
#define OUT_B2 983808    // + 192*1024
#define OFF1 25165824L   // 32*786432
#define OFF2 25190400L   // + 32*768
#define OFF3 31481856L   // + 32*196608

template<int CTRL>
__device__ __forceinline__ float pdpp(float x) {
    return __int_as_float(__builtin_amdgcn_update_dpp(
        0, __float_as_int(x), CTRL, 0xF, 0xF, true));
}

// H16 over the 16-register index (4 butterfly stages, pure VALU).
__device__ __forceinline__ void h16(float v[16]) {
    #pragma unroll
    for (int m = 1; m <= 8; m <<= 1) {
        #pragma unroll
        for (int r = 0; r < 16; ++r) {
            if (!(r & m)) {
                float a = v[r], b = v[r | m];
                v[r] = a + b;
                v[r | m] = a - b;
            }
        }
    }
}

// Butterflies on lane bits 0,1 via DPP quad_perm.
__device__ __forceinline__ void dpp2(float v[16], int lane) {
    const float s1 = (lane & 1) ? -1.f : 1.f;
    const float s2 = (lane & 2) ? -1.f : 1.f;
    #pragma unroll
    for (int r = 0; r < 16; ++r) { float p = pdpp<0xB1>(v[r]); v[r] = fmaf(s1, v[r], p); }
    #pragma unroll
    for (int r = 0; r < 16; ++r) { float p = pdpp<0x4E>(v[r]); v[r] = fmaf(s2, v[r], p); }
}

// Batched per-wave transpose through a private 1024-word LDS slice.
// In:  v[r]  = E[r*64 + lane]                          (M0)
// Out: v[rp] = E[(lane&3) | (rp<<2) | ((lane>>2)<<6)]  (M1)
// phys(i) = i ^ (((i>>6)&7)<<2): conflict-free on both sides.
__device__ __forceinline__ void wave_transpose(float v[16], float* ws, int lane) {
    #pragma unroll
    for (int r = 0; r < 16; ++r) {
        const int i = r * 64 + lane;
        ws[i ^ ((r & 7) << 2)] = v[r];
    }
    #pragma unroll
    for (int rp = 0; rp < 16; ++rp) {
        const int i = (lane & 3) | (rp << 2) | ((lane >> 2) << 6);
        v[rp] = ws[i ^ (((lane >> 2) & 7) << 2)];
    }
}

// Full FWHT-1024: M0 in, M1 out.
__device__ __forceinline__ void fwht1024(float v[16], float* ws, int lane) {
    h16(v);            // bits 6-9
    dpp2(v, lane);     // bits 0,1
    wave_transpose(v, ws, lane);
    h16(v);            // bits 2-5
}

// Shared out-tile swizzle: A = i*TS + col, phys2 = A ^ (((i>>6)&7)<<2).
__device__ __forceinline__ int phys2(int i, int col) {
    return (i * TS + col) ^ (((i >> 6) & 7) << 2);
}

// Pass 0: y_t[i*32+b] = fwht_1024(z[b]*BB[:1024])[i].  2 blocks x 16 waves.
__global__ __launch_bounds__(1024) void k_y(const float* __restrict__ z,
                                            const float* __restrict__ BBv,
                                            float* __restrict__ y_t) {
    __shared__ float tile[1024 * TS];
    const int tid = threadIdx.x;
    const int lane = tid & 63, w = tid >> 6;
    const int b = (blockIdx.x << 4) + w;
    float v[16];
    #pragma unroll
    for (int r = 0; r < 16; ++r) {
        const int i = r * 64 + lane;
        v[r] = z[(b << 10) + i] * BBv[i];
    }
    fwht1024(v, &tile[w << 10], lane);
    __syncthreads();                      // all private-slice reads done
    #pragma unroll
    for (int rp = 0; rp < 16; ++rp) {
        const int i = (lane & 3) | (rp << 2) | ((lane >> 2) << 6);
        tile[phys2(i, w)] = v[rp];
    }
    __syncthreads();
    const int bcol = tid & 15, i0 = tid >> 4;
    #pragma unroll 4
    for (int s = 0; s < 16; ++s) {
        const int i = i0 + (s << 6);
        y_t[(i << 5) + (blockIdx.x << 4) + bcol] = tile[phys2(i, bcol)];
    }
}

// Pass 1: block = (kh, bgroup of 16 b). Coalesced gather stage -> wave FWHT
// (M1 end) -> quad-segment fp16 U write.
__global__ __launch_bounds__(1024, 8) void k_pass1(const float* __restrict__ y_t,
                                                   const float* __restrict__ GG,
                                                   const int* __restrict__ Pi,
                                                   __half* __restrict__ U) {
    __shared__ float tile[1024 * TS];
    __shared__ float g_s[1024];
    __shared__ int   p_s[1024];
    const int tid = threadIdx.x;
    const int kh = blockIdx.x, bg = blockIdx.y;
    p_s[tid] = Pi[(kh << 10) + tid] & 1023;
    g_s[tid] = GG[(kh << 10) + tid];
    __syncthreads();
    const int b = tid & 15, kl0 = tid >> 4;
    #pragma unroll 4
    for (int s = 0; s < 16; ++s) {
        const int kl = kl0 + (s << 6);
        tile[kl * TS + b] = y_t[(p_s[kl] << 5) + (bg << 4) + b] * g_s[kl];
    }
    __syncthreads();
    const int lane = tid & 63, w = tid >> 6;
    float v[16];
    #pragma unroll
    for (int r = 0; r < 16; ++r) v[r] = tile[(r * 64 + lane) * TS + w];
    h16(v);
    dpp2(v, lane);
    __syncthreads();                      // all staging reads done before reuse
    wave_transpose(v, &tile[w << 10], lane);
    h16(v);
    const long ub = ((long)((bg << 4) + w) << 20) + ((long)kh << 10);
    __half* Up = U + ub + (lane & 3) + ((lane >> 2) << 6);
    #pragma unroll
    for (int rp = 0; rp < 16; ++rp) Up[rp << 2] = __float2half(v[rp]);
}

// Pass 2: block = (jl-tile of 16, b). Stage fp16 U (packed half2 loads) ->
// wave FWHT over kh (M1 end) -> swizzled shared out-transpose -> coalesced
// remapped f32 store.
__global__ __launch_bounds__(1024, 8) void k_pass2(const __half* __restrict__ U,
                                                   const float* __restrict__ divisor,
                                                   float* __restrict__ out) {
    __shared__ float tile[1024 * TS];
    const int tid = threadIdx.x;
    const int jl0 = blockIdx.x << 4;   // 0..1008 step 16
    const int bb  = blockIdx.y;        // 0..31
    const __half2* U2 = (const __half2*)(U + ((long)bb << 20));
    const int jp = tid & 7, k0 = tid >> 3;      // jl pair, kh base
    #pragma unroll 4
    for (int s = 0; s < 8; ++s) {
        const int kh = k0 + (s << 7);
        const float2 f = __half22float2(U2[((long)kh << 9) + (jl0 >> 1) + jp]);
        const int base = kh * TS + (jp << 1);
        tile[base]     = f.x;
        tile[base + 1] = f.y;
    }
    __syncthreads();
    const int lane = tid & 63, w = tid >> 6;
    float v[16];
    #pragma unroll
    for (int r = 0; r < 16; ++r) v[r] = tile[(r * 64 + lane) * TS + w];
    h16(v);
    dpp2(v, lane);
    __syncthreads();                      // staging reads done before reuse
    wave_transpose(v, &tile[w << 10], lane);
    h16(v);
    const float inv = 1.0f / (divisor[0] * sqrtf((float)TOTAL_DIM / 1048576.0f));
    __syncthreads();                      // private-slice reads done before out-tile
    #pragma unroll
    for (int rp = 0; rp < 16; ++rp) {
        const int jh = (lane & 3) | (rp << 2) | ((lane >> 2) << 6);
        tile[phys2(jh, w)] = v[rp] * inv;
    }
    __syncthreads();
    const int jl = tid & 15, kk0 = tid >> 4;
    #pragma unroll 2
    for (int s = 0; s < 16; ++s) {
        const int jh = kk0 + (s << 6);
        if (jh <= 960) {                                  // TOTAL = 961*1024
            const int j = (jh << 10) + jl0 + jl;
            long oidx;
            if (j < OUT_B0)      oidx = (long)bb * 786432 + j;
            else if (j < OUT_B1) oidx = OFF1 + (long)bb * 768 + (j - OUT_B0);
            else if (j < OUT_B2) oidx = OFF2 + (long)bb * 196608 + (j - OUT_B1);
            else                 oidx = OFF3 + (long)bb * 256 + (j - OUT_B2);
            out[oidx] = tile[phys2(jh, jl)];
        }
    }
}

extern "C" void kernel_launch(void* const* d_in, const int* in_sizes, int n_in,
                              void* d_out, int out_size, void* d_ws, size_t ws_size,
                              hipStream_t stream) {
    const float* z   = (const float*)d_in[0];   // [32,1024]
    const float* BBv = (const float*)d_in[1];   // [2^20]
    const float* GG  = (const float*)d_in[2];   // [2^20]
    const float* dv  = (const float*)d_in[3];   // [1]
    const int*   Pi  = (const int*)d_in[4];     // [2^20]
    float* out = (float*)d_out;

    float*  y_t = (float*)d_ws;                             // 32*1024 f32 = 128 KB
    __half* U   = (__half*)((char*)d_ws + (size_t)131072);  // 32*2^20 fp16 = 64 MB

    k_y<<<2, 1024, 0, stream>>>(z, BBv, y_t);
    k_pass1<<<dim3(1024, 2), 1024, 0, stream>>>(y_t, GG, Pi, U);
    k_pass2<<<dim3(64, 32), 1024, 0, stream>>>(U, dv, out);
}